// Round 7
// baseline (513.691 us; speedup 1.0000x reference)
//
#include <hip/hip_runtime.h>
#include <math.h>

#define BATCH 16
#define CIN   12
#define HH    256
#define WW    256
#define KK    9
#define HO    254
#define WO    254
#define PIX   (HO*WO)
#define COUT  16
#define CHW   (HH*WW)

typedef __attribute__((ext_vector_type(2))) float v2f;

__device__ __forceinline__ int iclamp(int v, int lo, int hi) {
    return v < lo ? lo : (v > hi ? hi : v);
}

// Pure-fp32 fused DCN, packed-math edition:
//  - all accumulators are v2f -> v_pk_fma_f32 (2 FMA/inst), numerics identical to scalar fp32
//  - conv0: offp[14] pairs; einsum: a1[8]/a2[8] output-channel pairs
//  - gathers in 2-channel batches (8 loads in flight) to stay L1-resident (R6 lesson:
//    24-wide batches blew L1, FETCH 144->346 MB)
__global__ __launch_bounds__(256, 4) void dcn_pk(
    const float* __restrict__ x,
    const float* __restrict__ w0, const float* __restrict__ b0,
    const float* __restrict__ w1, const float* __restrict__ b1,
    const float* __restrict__ w2, const float* __restrict__ b2,
    const float* __restrict__ w3, const float* __restrict__ b3,
    float* __restrict__ out)
{
    __shared__ float wc[KK*CIN*28];     // conv0 weights [k][c][o:28] (o<18 w0, 18..26 w2, 27 pad)
    __shared__ float ew[KK*CIN*32];     // einsum weights [k][c][j:32] (j<16 w1, j>=16 w3)

    const int tid = threadIdx.y*16 + threadIdx.x;

    for (int i = tid; i < KK*CIN*28; i += 256) {
        int k = i / (CIN*28);
        int r = i % (CIN*28);
        int c = r / 28;
        int o = r % 28;
        float v = 0.f;
        if (o < 18)      v = w0[(o*CIN + c)*KK + k];
        else if (o < 27) v = w2[((o-18)*CIN + c)*KK + k];
        wc[i] = v;
    }
    for (int i = tid; i < KK*CIN*32; i += 256) {
        int kc = i >> 5;
        int j  = i & 31;
        int k  = kc / CIN;
        int c  = kc % CIN;
        ew[i] = (j < 16) ? w1[(j*CIN + c)*KK + k]
                         : w3[((j-16)*CIN + c)*KK + k];
    }
    __syncthreads();

    const int b  = blockIdx.z;
    const int ho = blockIdx.y*16 + threadIdx.y;
    const int wo = blockIdx.x*16 + threadIdx.x;
    if (ho >= HO || wo >= WO) return;

    const float* xb = x + (size_t)b*CIN*CHW;

    // ---- phase 1: offset (18) + mask-logit (9) convs, packed pairs ----
    v2f offp[14];
    #pragma unroll
    for (int q = 0; q < 9; ++q)  { offp[q].x = b0[2*q];     offp[q].y = b0[2*q+1]; }
    #pragma unroll
    for (int q = 9; q < 13; ++q) { offp[q].x = b2[2*q-18];  offp[q].y = b2[2*q-17]; }
    offp[13].x = b2[8]; offp[13].y = 0.f;

    #pragma unroll
    for (int k = 0; k < 9; ++k) {
        const int ky = k / 3, kx = k % 3;
        const float* xt = xb + (size_t)(ho+ky)*WW + (wo+kx);
        float xv[CIN];
        #pragma unroll
        for (int c = 0; c < CIN; ++c) xv[c] = xt[(size_t)c*CHW];
        #pragma unroll
        for (int c = 0; c < CIN; ++c) {
            v2f vv; vv.x = xv[c]; vv.y = xv[c];
            const v2f* wrow = (const v2f*)&wc[(k*CIN + c)*28];
            #pragma unroll
            for (int q = 0; q < 14; ++q) offp[q] += wrow[q] * vv;
        }
    }

    float m[9];
    #pragma unroll
    for (int j = 0; j < 9; ++j) {
        const int idx = 18 + j;
        const float lg = (idx & 1) ? offp[idx >> 1].y : offp[idx >> 1].x;
        m[j] = 1.f / (1.f + expf(-lg));
    }

    // ---- phase 2: deformable sampling + dual einsum, packed ----
    v2f a1[8], a2[8];
    #pragma unroll
    for (int q = 0; q < 8; ++q) {
        a1[q].x = b1[2*q]; a1[q].y = b1[2*q+1];
        a2[q].x = b3[2*q]; a2[q].y = b3[2*q+1];
    }

    #pragma unroll
    for (int k = 0; k < 9; ++k) {
        const float py = offp[k].x + (float)(k/3) + (float)ho;
        const float px = offp[k].y + (float)(k%3) + (float)wo;
        const float y0f = floorf(py), x0f = floorf(px);
        const float fy = py - y0f, fx = px - x0f;
        const int y0 = (int)y0f, x0i = (int)x0f;
        const int y1 = y0 + 1,  x1i = x0i + 1;

        float w00 = (1.f-fy)*(1.f-fx);
        float w01 = (1.f-fy)*fx;
        float w10 = fy*(1.f-fx);
        float w11 = fy*fx;

        const bool vy0 = (unsigned)y0  < HH;
        const bool vy1 = (unsigned)y1  < HH;
        const bool vx0 = (unsigned)x0i < WW;
        const bool vx1 = (unsigned)x1i < WW;
        if (!(vy0 && vx0)) w00 = 0.f;
        if (!(vy0 && vx1)) w01 = 0.f;
        if (!(vy1 && vx0)) w10 = 0.f;
        if (!(vy1 && vx1)) w11 = 0.f;

        const int cy0 = iclamp(y0, 0, HH-1);
        const int cy1 = iclamp(y1, 0, HH-1);
        const int cx0 = iclamp(x0i, 0, WW-1);
        const int cx1 = iclamp(x1i, 0, WW-1);
        const int i00 = cy0*WW + cx0;
        const int i01 = cy0*WW + cx1;
        const int i10 = cy1*WW + cx0;
        const int i11 = cy1*WW + cx1;

        v2f w00p; w00p.x = w00; w00p.y = w00;
        v2f w01p; w01p.x = w01; w01p.y = w01;
        v2f w10p; w10p.x = w10; w10p.y = w10;
        v2f w11p; w11p.x = w11; w11p.y = w11;
        v2f mkp;  mkp.x  = m[k]; mkp.y = m[k];

        #pragma unroll
        for (int cp = 0; cp < 6; ++cp) {            // 2 channels per iter, 8 loads in flight
            const float* xc0 = xb + (size_t)(2*cp)*CHW;
            const float* xc1 = xc0 + CHW;
            const float a00 = xc0[i00], a01 = xc0[i01], a10 = xc0[i10], a11 = xc0[i11];
            const float c00 = xc1[i00], c01 = xc1[i01], c10 = xc1[i10], c11 = xc1[i11];

            v2f G00; G00.x = a00; G00.y = c00;
            v2f G01; G01.x = a01; G01.y = c01;
            v2f G10; G10.x = a10; G10.y = c10;
            v2f G11; G11.x = a11; G11.y = c11;

            v2f vp = G00 * w00p;
            vp += G01 * w01p;
            vp += G10 * w10p;
            vp += G11 * w11p;
            v2f vmp = vp * mkp;

            // channel 2cp
            {
                v2f v0;  v0.x  = vp.x;  v0.y  = vp.x;
                v2f v0m; v0m.x = vmp.x; v0m.y = vmp.x;
                const v2f* wr = (const v2f*)&ew[(k*CIN + 2*cp)*32];
                #pragma unroll
                for (int q = 0; q < 8; ++q) {
                    a1[q] += wr[q]     * v0;
                    a2[q] += wr[8 + q] * v0m;
                }
            }
            // channel 2cp+1
            {
                v2f v1;  v1.x  = vp.y;  v1.y  = vp.y;
                v2f v1m; v1m.x = vmp.y; v1m.y = vmp.y;
                const v2f* wr = (const v2f*)&ew[(k*CIN + 2*cp + 1)*32];
                #pragma unroll
                for (int q = 0; q < 8; ++q) {
                    a1[q] += wr[q]     * v1;
                    a2[q] += wr[8 + q] * v1m;
                }
            }
        }
    }

    // ---- store: x1 then x2, each [B][16][254][254] (wave-coalesced dwords) ----
    const size_t p = (size_t)ho*WO + wo;
    float* o1 = out + (size_t)b*COUT*PIX + p;
    float* o2 = o1 + (size_t)BATCH*COUT*PIX;
    #pragma unroll
    for (int q = 0; q < 8; ++q) {
        o1[(size_t)(2*q)*PIX]   = a1[q].x;
        o1[(size_t)(2*q+1)*PIX] = a1[q].y;
        o2[(size_t)(2*q)*PIX]   = a2[q].x;
        o2[(size_t)(2*q+1)*PIX] = a2[q].y;
    }
}

extern "C" void kernel_launch(void* const* d_in, const int* in_sizes, int n_in,
                              void* d_out, int out_size, void* d_ws, size_t ws_size,
                              hipStream_t stream) {
    const float* x  = (const float*)d_in[0];
    const float* w0 = (const float*)d_in[1];
    const float* b0 = (const float*)d_in[2];
    const float* w1 = (const float*)d_in[3];
    const float* b1 = (const float*)d_in[4];
    const float* w2 = (const float*)d_in[5];
    const float* b2 = (const float*)d_in[6];
    const float* w3 = (const float*)d_in[7];
    const float* b3 = (const float*)d_in[8];
    float* out = (float*)d_out;

    dim3 block(16, 16);
    dim3 grid((WO + 15)/16, (HO + 15)/16, BATCH);
    dcn_pk<<<grid, block, 0, stream>>>(x, w0, b0, w1, b1, w2, b2, w3, b3, out);
}